// Round 14
// baseline (568.907 us; speedup 1.0000x reference)
//
#include <hip/hip_runtime.h>
#include <math.h>

typedef unsigned short u16;
typedef unsigned int u32;

typedef __attribute__((ext_vector_type(8))) short short8;
typedef __attribute__((ext_vector_type(4))) float floatx4;

#define NTILES 16384  // B*N*N/64

__device__ __forceinline__ float bfu(u16 u) { return __uint_as_float(((u32)u) << 16); }
__device__ __forceinline__ u16 f2bfs(float f) {
  u32 x = __float_as_uint(f);
  return (u16)((x + 0x7FFFu + ((x >> 16) & 1u)) >> 16);
}
__device__ __forceinline__ float tanh_fast(float x) {
  float e = __builtin_amdgcn_exp2f(x * 2.885390081777927f);
  return 1.0f - 2.0f * __builtin_amdgcn_rcpf(e + 1.0f);
}

// ------ edge MLP -> e_sum (R8-proven core; 8-way qt split kept for profiler
// visibility of the smaller kernels) ------------------------------------------
__global__ __attribute__((amdgpu_flat_work_group_size(1024, 1024)))
__attribute__((amdgpu_waves_per_eu(4, 4)))
void k_edge(const float* __restrict__ ef,
    const float* __restrict__ w1, const float* __restrict__ b1,
    const float* __restrict__ w2, const float* __restrict__ b2,
    float* __restrict__ es32, u16* __restrict__ es16, int use16,
    int qt0, int qt1) {
  __shared__ __align__(16) short T1[16 * 2048];   // per-wave 4KB
  __shared__ __align__(16) short W2L[16384];      // swizzled
  __shared__ __align__(16) short W1L[2 * 2056];
  __shared__ __align__(16) float B1L[256];
  __shared__ __align__(16) float B2L[64];
  int t = threadIdx.x;
  int lane = t & 63, w = t >> 6, q = lane >> 4, r = lane & 15;

  for (int u = 0; u < 16; ++u) {
    int flat = u * 1024 + t;
    int k = flat >> 6, n = flat & 63;
    int c = k >> 3, j = k & 7;
    int physc = (c & 16) | ((c & 15) ^ (n & 15));
    W2L[(n * 32 + physc) * 8 + j] = (short)f2bfs(w2[flat]);
  }
  if (t < 512) {
    int hilo = t >> 8, idx = t & 255;
    int gu = idx >> 4, rr = idx & 15;
    int feat = (gu < 8) ? (rr * 8 + gu) : (120 + rr * 8 + gu);
    short8 v;
#pragma unroll
    for (int j = 0; j < 8; ++j) {
      float x = w1[j * 256 + feat];
      u32 xb = __float_as_uint(x);
      u16 hi = (u16)(xb >> 16);
      v[j] = hilo ? (short)f2bfs(x - bfu(hi)) : (short)hi;
    }
    *(short8*)&W1L[hilo * 2056 + idx * 8] = v;
  }
  if (t < 256) B1L[t] = b1[t];
  if (t < 64)  B2L[t] = b2[t];
  __syncthreads();

  short* t1w = &T1[w * 2048];
  const int hb = (q >> 1) * 2056;
  const int nw = gridDim.x * 16;
  int qt = qt0 + blockIdx.x * 16 + w;
  float4 e0, e1;
  {
    const float4* ep = (const float4*)(ef + (size_t)qt * 128 + (size_t)r * 8);
    e0 = ep[0]; e1 = ep[1];
  }

  for (; qt < qt1; qt += nw) {
    float ev[8] = {e0.x, e0.y, e0.z, e0.w, e1.x, e1.y, e1.z, e1.w};
    short8 af1;
#pragma unroll
    for (int j = 0; j < 8; ++j) {
      u32 xb = __float_as_uint(ev[j]);
      u16 hi = (u16)(xb >> 16);
      af1[j] = (q & 1) ? (short)f2bfs(ev[j] - bfu(hi)) : (short)hi;
    }
    int nqt = qt + nw;
    if (nqt < qt1) {
      const float4* ep = (const float4*)(ef + (size_t)nqt * 128 + (size_t)r * 8);
      e0 = ep[0]; e1 = ep[1];
    }
    floatx4 acc4[4];
#pragma unroll
    for (int nt = 0; nt < 4; ++nt) acc4[nt] = (floatx4){0.f, 0.f, 0.f, 0.f};
#pragma unroll
    for (int ph = 0; ph < 2; ++ph) {
      floatx4 c1[8];
#pragma unroll
      for (int u = 0; u < 8; ++u) c1[u] = (floatx4){0.f, 0.f, 0.f, 0.f};
#pragma unroll
      for (int u = 0; u < 8; ++u) {
        short8 bf = *(const short8*)&W1L[hb + ((ph * 8 + u) * 16 + r) * 8];
        c1[u] = __builtin_amdgcn_mfma_f32_16x16x32_bf16(af1, bf, c1[u], 0, 0, 0);
      }
      asm volatile("s_waitcnt lgkmcnt(0)" ::: "memory");
      __builtin_amdgcn_sched_barrier(0);
      const float4* bp = (const float4*)&B1L[ph * 128 + r * 8];
      float4 bA = bp[0], bB = bp[1];
      float bias[8] = {bA.x, bA.y, bA.z, bA.w, bB.x, bB.y, bB.z, bB.w};
#pragma unroll
      for (int reg = 0; reg < 4; ++reg) {
        u32 pk[4];
#pragma unroll
        for (int p2 = 0; p2 < 4; ++p2) {
          float va = tanh_fast(c1[2 * p2][reg] + bias[2 * p2]);
          float vb = tanh_fast(c1[2 * p2 + 1][reg] + bias[2 * p2 + 1]);
          u32 pr;
          asm("v_cvt_pk_bf16_f32 %0, %1, %2" : "=v"(pr) : "v"(va), "v"(vb));
          pk[p2] = pr;
        }
        int row = q * 4 + reg;
        int physc = r ^ row;
        int4 wa; wa.x = (int)pk[0]; wa.y = (int)pk[1]; wa.z = (int)pk[2]; wa.w = (int)pk[3];
        *(int4*)&t1w[(row * 16 + physc) * 8] = wa;
      }
      asm volatile("s_waitcnt lgkmcnt(0)" ::: "memory");
      __builtin_amdgcn_sched_barrier(0);
#pragma unroll
      for (int sm = 0; sm < 4; ++sm) {
        int cc = (4 * sm + q) ^ r;
        short8 af = *(const short8*)&t1w[(r * 16 + cc) * 8];
        int wc = ph * 16 + cc;
#pragma unroll
        for (int nt = 0; nt < 4; ++nt) {
          short8 bf = *(const short8*)&W2L[((nt * 16 + r) * 32 + wc) * 8];
          acc4[nt] = __builtin_amdgcn_mfma_f32_16x16x32_bf16(af, bf, acc4[nt], 0, 0, 0);
        }
      }
    }
    float s0 = 0.f, s1 = 0.f, s2 = 0.f, s3 = 0.f;
#pragma unroll
    for (int nt = 0; nt < 4; ++nt) {
      float bb = B2L[nt * 16 + r];
      s0 += tanh_fast(acc4[nt][0] + bb);
      s1 += tanh_fast(acc4[nt][1] + bb);
      s2 += tanh_fast(acc4[nt][2] + bb);
      s3 += tanh_fast(acc4[nt][3] + bb);
    }
#pragma unroll
    for (int off = 1; off < 16; off <<= 1) {
      s0 += __shfl_xor(s0, off, 64);
      s1 += __shfl_xor(s1, off, 64);
      s2 += __shfl_xor(s2, off, 64);
      s3 += __shfl_xor(s3, off, 64);
    }
    if (r == 0) {
      int base = qt * 16 + q * 4;
      if (use16) {
        es16[base] = f2bfs(s0); es16[base + 1] = f2bfs(s1);
        es16[base + 2] = f2bfs(s2); es16[base + 3] = f2bfs(s3);
      } else {
        float4 o; o.x = s0; o.y = s1; o.z = s2; o.w = s3;
        *(float4*)&es32[base] = o;
      }
    }
  }
}

// ---- k_pre: node embed MLP + gcn_tmp(l=0) + dinv + counter zero --------------
__global__ __launch_bounds__(256) void k_pre(const float* __restrict__ nf,
    const float* __restrict__ w1, const float* __restrict__ b1,
    const float* __restrict__ w2, const float* __restrict__ b2,
    const float* __restrict__ gw, const float* __restrict__ adj,
    float* __restrict__ hid, u16* __restrict__ alls16, float* __restrict__ tmp,
    float* __restrict__ dinv, int* __restrict__ cnt) {
  __shared__ float nfx[4][16];
  __shared__ float t1[4][256];
  __shared__ float nh[4][64];
  int t = threadIdx.x;
  int node0 = blockIdx.x * 4;
  if (blockIdx.x == 0 && t < 16) cnt[t] = 0;
  if (t < 64) nfx[t >> 4][t & 15] = nf[node0 * 16 + t];
  __syncthreads();
  float b1t = b1[t];
  float a0 = b1t, a1 = b1t, a2 = b1t, a3 = b1t;
#pragma unroll
  for (int c = 0; c < 16; ++c) {
    float wv = w1[c * 256 + t];
    a0 += nfx[0][c] * wv; a1 += nfx[1][c] * wv;
    a2 += nfx[2][c] * wv; a3 += nfx[3][c] * wv;
  }
  t1[0][t] = tanh_fast(a0); t1[1][t] = tanh_fast(a1);
  t1[2][t] = tanh_fast(a2); t1[3][t] = tanh_fast(a3);
  __syncthreads();
  int nl = t >> 6, h = t & 63;
  {
    float acc = b2[h];
    for (int c = 0; c < 256; c += 4) {
      float4 xv = *(const float4*)&t1[nl][c];
      acc += xv.x * w2[c * 64 + h] + xv.y * w2[(c + 1) * 64 + h]
           + xv.z * w2[(c + 2) * 64 + h] + xv.w * w2[(c + 3) * 64 + h];
    }
    float v = tanh_fast(acc);
    int node = node0 + nl;
    hid[node * 64 + h] = v;
    alls16[node * 256 + h] = f2bfs(v);
    nh[nl][h] = v;
  }
  __syncthreads();
  {
    float g = 0.f;
    for (int c = 0; c < 64; ++c) g += nh[nl][c] * gw[c * 64 + h];
    tmp[(node0 + nl) * 64 + h] = g;
  }
  {
    int lane = t & 63, row = node0 + (t >> 6);
    float s = 0.f;
#pragma unroll
    for (int u = 0; u < 8; ++u) s += adj[(size_t)row * 512 + u * 64 + lane];
#pragma unroll
    for (int off = 32; off > 0; off >>= 1) s += __shfl_xor(s, off, 64);
    if (lane == 0) dinv[row] = 1.0f / (s + 1.0f);
  }
}

// ------- adjmm0 R14: streaming, sync-free. One wave = one row, lane = feature.
// grid 512 (4 rows/block, 2 blocks/CU = 8 waves/CU). No LDS X staging.
__global__ __launch_bounds__(256) void k_adjmm0(const float* __restrict__ adj,
    const float* __restrict__ X, const float* __restrict__ dinv,
    float* __restrict__ out, float* __restrict__ vnpart, int* cnt,
    const float* __restrict__ vw1, const float* __restrict__ vb1,
    const float* __restrict__ vg1, const float* __restrict__ vbe1,
    const float* __restrict__ vw2, const float* __restrict__ vb2,
    const float* __restrict__ vg2, const float* __restrict__ vbe2,
    float* __restrict__ vnout, int l) {
  __shared__ float vnp[4][64];
  __shared__ float buf[1536];   // vn-MLP tail scratch
  __shared__ int isLast;
  int t = threadIdx.x;
  int w = t >> 6, lane = t & 63;
  int b = blockIdx.x >> 7, blk = blockIdx.x & 127;
  int row = b * 512 + blk * 4 + w;
  float d = dinv[row];
  const float* ar = adj + (size_t)row * 512;
  const float* xb = X + (size_t)b * 512 * 64;
  float acc = 0.f;
#pragma unroll 4
  for (int j = 0; j < 512; j += 4) {
    float4 a4 = *(const float4*)(ar + j);
    float x0 = xb[(j + 0) * 64 + lane];
    float x1 = xb[(j + 1) * 64 + lane];
    float x2 = xb[(j + 2) * 64 + lane];
    float x3 = xb[(j + 3) * 64 + lane];
    acc += a4.x * x0 + a4.y * x1 + a4.z * x2 + a4.w * x3;
  }
  float o = tanh_fast(acc * d);
  out[(size_t)row * 64 + lane] = o;
  vnp[w][lane] = o;
  __syncthreads();
  if (t < 64) {
    float s = vnp[0][t] + vnp[1][t] + vnp[2][t] + vnp[3][t];
    vnpart[(b * 128 + blk) * 64 + t] = s;
  }
  __threadfence();
  __syncthreads();
  if (t == 0) isLast = (atomicAdd(cnt, 1) == 511);
  __syncthreads();
  if (isLast) {
    __threadfence();
    float* x0 = buf; float* x1 = buf + 256; float* y1 = buf + 768; float* x2 = buf + 1280;
    {
      int bb = t >> 6, h = t & 63;
      float s = 0.f;
      for (int c = 0; c < 128; ++c) s += vnpart[(bb * 128 + c) * 64 + h];
      x0[t] = s * (1.0f / 512.0f);
    }
    __syncthreads();
    for (int rep = 0; rep < 2; ++rep) {
      int idx = rep * 256 + t;
      int bb = idx >> 7, j = idx & 127;
      float a = vb1[l * 128 + j];
      for (int h = 0; h < 64; ++h) a += x0[bb * 64 + h] * vw1[l * 8192 + h * 128 + j];
      x1[idx] = a;
    }
    __syncthreads();
    if (t < 128) {
      int j = t;
      float a = x1[j], bq = x1[128 + j], c = x1[256 + j], d2 = x1[384 + j];
      float m = 0.25f * (a + bq + c + d2);
      float da = a - m, db = bq - m, dc = c - m, dd = d2 - m;
      float var = 0.25f * (da * da + db * db + dc * dc + dd * dd);
      float sc = vg1[l * 128 + j] / sqrtf(var + 1e-5f);
      float be = vbe1[l * 128 + j];
      y1[j]       = fmaxf(sc * da + be, 0.f);
      y1[128 + j] = fmaxf(sc * db + be, 0.f);
      y1[256 + j] = fmaxf(sc * dc + be, 0.f);
      y1[384 + j] = fmaxf(sc * dd + be, 0.f);
    }
    __syncthreads();
    {
      int bb = t >> 6, k = t & 63;
      float a = vb2[l * 64 + k];
      for (int j = 0; j < 128; ++j) a += y1[bb * 128 + j] * vw2[l * 8192 + j * 64 + k];
      x2[t] = a;
    }
    __syncthreads();
    if (t < 64) {
      int k = t;
      float a = x2[k], bq = x2[64 + k], c = x2[128 + k], d2 = x2[192 + k];
      float m = 0.25f * (a + bq + c + d2);
      float da = a - m, db = bq - m, dc = c - m, dd = d2 - m;
      float var = 0.25f * (da * da + db * db + dc * dc + dd * dd);
      float sc = vg2[l * 64 + k] / sqrtf(var + 1e-5f);
      float be = vbe2[l * 64 + k];
      vnout[k]       = fmaxf(sc * da + be, 0.f);
      vnout[64 + k]  = fmaxf(sc * db + be, 0.f);
      vnout[128 + k] = fmaxf(sc * dc + be, 0.f);
      vnout[192 + k] = fmaxf(sc * dd + be, 0.f);
    }
  }
}

// ------- k_gate_comb R14: streaming wave-per-row; comb/gcn via wave-local LDS
// (lgkmcnt fences, no block syncs). gated = tanh(sum a_j*h_j + (sum a_j)*vn).
__global__ __launch_bounds__(256) void k_gate_comb(
    const float* __restrict__ es32, const u16* __restrict__ es16, int use16,
    const float* __restrict__ hid, const float* __restrict__ vnin,
    const float* __restrict__ cw, const float* __restrict__ cb,
    const float* __restrict__ gw_next,
    u16* __restrict__ alls16, float* __restrict__ tmpout, int l, int do_gcn) {
  __shared__ float catL[4][128];
  __shared__ float hnL[4][64];
  int t = threadIdx.x;
  int w = t >> 6, lane = t & 63;
  int b = blockIdx.x >> 7, blk = blockIdx.x & 127;
  int row = b * 512 + blk * 4 + w;
  float vnl = vnin[b * 64 + lane];
  const float* hb = hid + (size_t)b * 512 * 64;
  float acc = 0.f, asum = 0.f;
  if (use16) {
    const u16* er = es16 + (size_t)row * 512;
#pragma unroll 4
    for (int j = 0; j < 512; j += 4) {
      uint2 u2 = *(const uint2*)(er + j);
      float a0 = bfu((u16)(u2.x & 0xffffu)), a1 = bfu((u16)(u2.x >> 16));
      float a2 = bfu((u16)(u2.y & 0xffffu)), a3 = bfu((u16)(u2.y >> 16));
      acc += a0 * hb[(j + 0) * 64 + lane] + a1 * hb[(j + 1) * 64 + lane]
           + a2 * hb[(j + 2) * 64 + lane] + a3 * hb[(j + 3) * 64 + lane];
      asum += (a0 + a1) + (a2 + a3);
    }
  } else {
    const float* er = es32 + (size_t)row * 512;
#pragma unroll 4
    for (int j = 0; j < 512; j += 4) {
      float4 a4 = *(const float4*)(er + j);
      acc += a4.x * hb[(j + 0) * 64 + lane] + a4.y * hb[(j + 1) * 64 + lane]
           + a4.z * hb[(j + 2) * 64 + lane] + a4.w * hb[(j + 3) * 64 + lane];
      asum += (a4.x + a4.y) + (a4.z + a4.w);
    }
  }
  float gated = tanh_fast(acc + asum * vnl);
  catL[w][lane] = hid[(size_t)row * 64 + lane] + vnl;
  catL[w][64 + lane] = gated;
  asm volatile("s_waitcnt lgkmcnt(0)" ::: "memory");
  __builtin_amdgcn_sched_barrier(0);
  // comb: one output feature per lane
  float a = cb[l * 64 + lane];
  const float* wp = cw + l * 8192 + lane;
#pragma unroll 4
  for (int c = 0; c < 128; ++c) a += catL[w][c] * wp[c * 64];
  float v = tanh_fast(a);
  alls16[(size_t)row * 256 + (l + 1) * 64 + lane] = f2bfs(v);
  if (do_gcn) {
    hnL[w][lane] = v;
    asm volatile("s_waitcnt lgkmcnt(0)" ::: "memory");
    __builtin_amdgcn_sched_barrier(0);
    float g = 0.f;
#pragma unroll 4
    for (int c = 0; c < 64; ++c) g += hnL[w][c] * gw_next[c * 64 + lane];
    tmpout[(size_t)row * 64 + lane] = g;
  }
}

// ---- k_lat: latent MLP main body (512 threads, R13-proven) ------------------
__global__ __launch_bounds__(512) void k_lat(const u16* __restrict__ alls16,
    const float* __restrict__ w1, const float* __restrict__ bb1,
    const float* __restrict__ w2, const float* __restrict__ bb2,
    float* __restrict__ latpart) {
  __shared__ float x[8][256];
  __shared__ float t1[8][256];
  __shared__ float red[8][256];
  int t = threadIdx.x;
  int g = t >> 8, tt = t & 255;
  int b = blockIdx.x >> 6, chunk = blockIdx.x & 63;
#pragma unroll
  for (int u = 0; u < 4; ++u)
    x[g * 4 + u][tt] = bfu(alls16[(size_t)(b * 512 + chunk * 8 + g * 4 + u) * 256 + tt]);
  __syncthreads();
  float a1[4];
  float bb = bb1[tt];
#pragma unroll
  for (int u = 0; u < 4; ++u) a1[u] = bb;
  for (int c = 0; c < 256; ++c) {
    float wv = w1[c * 256 + tt];
#pragma unroll
    for (int u = 0; u < 4; ++u) a1[u] += x[g * 4 + u][c] * wv;
  }
#pragma unroll
  for (int u = 0; u < 4; ++u) t1[g * 4 + u][tt] = tanh_fast(a1[u]);
  __syncthreads();
  int quar = tt >> 6, k = tt & 63, c0 = quar * 64;
  float a2[4];
#pragma unroll
  for (int u = 0; u < 4; ++u) a2[u] = 0.f;
  for (int c = 0; c < 64; ++c) {
    float wv = w2[(c0 + c) * 64 + k];
#pragma unroll
    for (int u = 0; u < 4; ++u) a2[u] += t1[g * 4 + u][c0 + c] * wv;
  }
#pragma unroll
  for (int u = 0; u < 4; ++u) red[g * 4 + u][tt] = a2[u];
  __syncthreads();
  if (t < 64) {
    float acc2 = 0.f;
    float b2v = bb2[t];
#pragma unroll
    for (int u = 0; u < 8; ++u) {
      float s = red[u][t] + red[u][t + 64] + red[u][t + 128] + red[u][t + 192] + b2v;
      acc2 += tanh_fast(s);
    }
    latpart[(b * 64 + chunk) * 64 + t] = acc2;
  }
}

// ---- k_final: lat_sum + fc head, grid 4 (one block per batch) ---------------
__global__ __launch_bounds__(512) void k_final(const float* __restrict__ latpart,
    const float* __restrict__ f1w, const float* __restrict__ f1b,
    const float* __restrict__ f2w, const float* __restrict__ f2b,
    float* __restrict__ outp) {
  __shared__ float lred[512];
  __shared__ float ls[64];
  __shared__ float wred[8];
  int b = blockIdx.x, t = threadIdx.x;
  int z = t & 63, cg = t >> 6;
  float s = 0.f;
  for (int c = cg * 8; c < cg * 8 + 8; ++c) s += latpart[(b * 64 + c) * 64 + z];
  lred[t] = s;
  __syncthreads();
  if (t < 64) {
    float ssum = 0.f;
    for (int gg = 0; gg < 8; ++gg) ssum += lred[gg * 64 + t];
    ls[t] = ssum;
    outp[4 + b * 64 + t] = ssum;   // lat_sum (fp32)
  }
  __syncthreads();
  float acc = f1b[t];
  for (int zz = 0; zz < 64; ++zz) acc += ls[zz] * f1w[zz * 512 + t];
  float h = tanh_fast(acc);
  float p = h * f2w[t];
#pragma unroll
  for (int off = 32; off > 0; off >>= 1) p += __shfl_xor(p, off, 64);
  if ((t & 63) == 0) wred[t >> 6] = p;
  __syncthreads();
  if (t == 0) {
    float a = 0.f;
    for (int wv = 0; wv < 8; ++wv) a += wred[wv];
    outp[b] = a + f2b[0];   // predict (fp32)
  }
}

extern "C" void kernel_launch(void* const* d_in, const int* in_sizes, int n_in,
                              void* d_out, int out_size, void* d_ws, size_t ws_size,
                              hipStream_t stream) {
  const float* adj       = (const float*)d_in[0];
  const float* node_feat = (const float*)d_in[1];
  const float* edge_feat = (const float*)d_in[2];
  const float* nf1_w = (const float*)d_in[3];
  const float* nf1_b = (const float*)d_in[4];
  const float* nf2_w = (const float*)d_in[5];
  const float* nf2_b = (const float*)d_in[6];
  const float* ef1_w = (const float*)d_in[7];
  const float* ef1_b = (const float*)d_in[8];
  const float* ef2_w = (const float*)d_in[9];
  const float* ef2_b = (const float*)d_in[10];
  const float* gcn_w = (const float*)d_in[11];
  const float* vn1_w = (const float*)d_in[12];
  const float* vn1_b = (const float*)d_in[13];
  const float* vn1_g = (const float*)d_in[14];
  const float* vn1_be = (const float*)d_in[15];
  const float* vn2_w = (const float*)d_in[16];
  const float* vn2_b = (const float*)d_in[17];
  const float* vn2_g = (const float*)d_in[18];
  const float* vn2_be = (const float*)d_in[19];
  const float* comb_w = (const float*)d_in[20];
  const float* comb_b = (const float*)d_in[21];
  const float* lat1_w = (const float*)d_in[22];
  const float* lat1_b = (const float*)d_in[23];
  const float* lat2_w = (const float*)d_in[24];
  const float* lat2_b = (const float*)d_in[25];
  const float* fc1_w = (const float*)d_in[26];
  const float* fc1_b = (const float*)d_in[27];
  const float* fc2_w = (const float*)d_in[28];
  const float* fc2_b = (const float*)d_in[29];

  const int use16 = (ws_size < (size_t)12 * 1024 * 1024) ? 1 : 0;
  char* p = (char*)d_ws;
  float* es32 = (float*)p;
  u16*   es16 = (u16*)p;
  size_t es_bytes = use16 ? (size_t)1048576 * 2 : (size_t)1048576 * 4;
  u16*   alls16  = (u16*)(p + es_bytes);      // 524288 u16
  float* hid     = (float*)(alls16 + 524288); // 131072 f32
  float* tmp     = hid + 131072;              // 131072 (gcn tmp)
  float* dinv    = tmp + 131072;              // 2048
  float* vnpart  = dinv + 2048;               // 32768 (512 chunks x 64)
  float* vn      = vnpart + 32768;            // 256
  float* latpart = vn + 256;                  // 16384
  int*   cnt     = (int*)(latpart + 16384);   // 16

  k_pre<<<512, 256, 0, stream>>>(node_feat, nf1_w, nf1_b, nf2_w, nf2_b,
                                 gcn_w, adj, hid, alls16, tmp, dinv, cnt);
  for (int d = 0; d < 8; ++d)
    k_edge<<<256, 1024, 0, stream>>>(edge_feat, ef1_w, ef1_b, ef2_w, ef2_b,
                                     es32, es16, use16,
                                     d * 8192, (d + 1) * 8192);
  for (int l = 0; l < 3; ++l) {
    k_adjmm0<<<512, 256, 0, stream>>>(adj, tmp, dinv, hid, vnpart, cnt + l,
        vn1_w, vn1_b, vn1_g, vn1_be, vn2_w, vn2_b, vn2_g, vn2_be, vn, l);
    k_gate_comb<<<512, 256, 0, stream>>>(es32, es16, use16, hid, vn,
        comb_w, comb_b, gcn_w + (l + 1) * 4096, alls16, tmp, l, (l < 2) ? 1 : 0);
  }
  k_lat<<<256, 512, 0, stream>>>(alls16, lat1_w, lat1_b, lat2_w, lat2_b, latpart);
  k_final<<<4, 512, 0, stream>>>(latpart, fc1_w, fc1_b, fc2_w, fc2_b,
                                 (float*)d_out);
}

// Round 15
// 435.554 us; speedup vs baseline: 1.3062x; 1.3062x over previous
//
#include <hip/hip_runtime.h>
#include <math.h>

typedef unsigned short u16;
typedef unsigned int u32;

typedef __attribute__((ext_vector_type(8))) short short8;
typedef __attribute__((ext_vector_type(4))) float floatx4;

#define NTILES 16384  // B*N*N/64

__device__ __forceinline__ float bfu(u16 u) { return __uint_as_float(((u32)u) << 16); }
__device__ __forceinline__ u16 f2bfs(float f) {
  u32 x = __float_as_uint(f);
  return (u16)((x + 0x7FFFu + ((x >> 16) & 1u)) >> 16);
}
__device__ __forceinline__ float tanh_fast(float x) {
  float e = __builtin_amdgcn_exp2f(x * 2.885390081777927f);
  return 1.0f - 2.0f * __builtin_amdgcn_rcpf(e + 1.0f);
}

// ------ edge MLP -> e_sum (R8-proven: ~131us, transcendental-pipe floor) -----
__global__ __attribute__((amdgpu_flat_work_group_size(1024, 1024)))
__attribute__((amdgpu_waves_per_eu(4, 4)))
void k_edge(const float* __restrict__ ef,
    const float* __restrict__ w1, const float* __restrict__ b1,
    const float* __restrict__ w2, const float* __restrict__ b2,
    float* __restrict__ es32, u16* __restrict__ es16, int use16) {
  __shared__ __align__(16) short T1[16 * 2048];   // per-wave 4KB
  __shared__ __align__(16) short W2L[16384];      // swizzled
  __shared__ __align__(16) short W1L[2 * 2056];
  __shared__ __align__(16) float B1L[256];
  __shared__ __align__(16) float B2L[64];
  int t = threadIdx.x;
  int lane = t & 63, w = t >> 6, q = lane >> 4, r = lane & 15;

  for (int u = 0; u < 16; ++u) {
    int flat = u * 1024 + t;
    int k = flat >> 6, n = flat & 63;
    int c = k >> 3, j = k & 7;
    int physc = (c & 16) | ((c & 15) ^ (n & 15));
    W2L[(n * 32 + physc) * 8 + j] = (short)f2bfs(w2[flat]);
  }
  if (t < 512) {
    int hilo = t >> 8, idx = t & 255;
    int gu = idx >> 4, rr = idx & 15;
    int feat = (gu < 8) ? (rr * 8 + gu) : (120 + rr * 8 + gu);
    short8 v;
#pragma unroll
    for (int j = 0; j < 8; ++j) {
      float x = w1[j * 256 + feat];
      u32 xb = __float_as_uint(x);
      u16 hi = (u16)(xb >> 16);
      v[j] = hilo ? (short)f2bfs(x - bfu(hi)) : (short)hi;
    }
    *(short8*)&W1L[hilo * 2056 + idx * 8] = v;
  }
  if (t < 256) B1L[t] = b1[t];
  if (t < 64)  B2L[t] = b2[t];
  __syncthreads();

  short* t1w = &T1[w * 2048];
  const int hb = (q >> 1) * 2056;
  const int nw = gridDim.x * 16;
  int qt = blockIdx.x * 16 + w;
  float4 e0, e1;
  {
    const float4* ep = (const float4*)(ef + (size_t)qt * 128 + (size_t)r * 8);
    e0 = ep[0]; e1 = ep[1];
  }

  for (; qt < 4 * NTILES; qt += nw) {
    float ev[8] = {e0.x, e0.y, e0.z, e0.w, e1.x, e1.y, e1.z, e1.w};
    short8 af1;
#pragma unroll
    for (int j = 0; j < 8; ++j) {
      u32 xb = __float_as_uint(ev[j]);
      u16 hi = (u16)(xb >> 16);
      af1[j] = (q & 1) ? (short)f2bfs(ev[j] - bfu(hi)) : (short)hi;
    }
    int nqt = qt + nw;
    if (nqt < 4 * NTILES) {
      const float4* ep = (const float4*)(ef + (size_t)nqt * 128 + (size_t)r * 8);
      e0 = ep[0]; e1 = ep[1];
    }
    floatx4 acc4[4];
#pragma unroll
    for (int nt = 0; nt < 4; ++nt) acc4[nt] = (floatx4){0.f, 0.f, 0.f, 0.f};
#pragma unroll
    for (int ph = 0; ph < 2; ++ph) {
      floatx4 c1[8];
#pragma unroll
      for (int u = 0; u < 8; ++u) c1[u] = (floatx4){0.f, 0.f, 0.f, 0.f};
#pragma unroll
      for (int u = 0; u < 8; ++u) {
        short8 bf = *(const short8*)&W1L[hb + ((ph * 8 + u) * 16 + r) * 8];
        c1[u] = __builtin_amdgcn_mfma_f32_16x16x32_bf16(af1, bf, c1[u], 0, 0, 0);
      }
      asm volatile("s_waitcnt lgkmcnt(0)" ::: "memory");
      __builtin_amdgcn_sched_barrier(0);
      const float4* bp = (const float4*)&B1L[ph * 128 + r * 8];
      float4 bA = bp[0], bB = bp[1];
      float bias[8] = {bA.x, bA.y, bA.z, bA.w, bB.x, bB.y, bB.z, bB.w};
#pragma unroll
      for (int reg = 0; reg < 4; ++reg) {
        u32 pk[4];
#pragma unroll
        for (int p2 = 0; p2 < 4; ++p2) {
          float va = tanh_fast(c1[2 * p2][reg] + bias[2 * p2]);
          float vb = tanh_fast(c1[2 * p2 + 1][reg] + bias[2 * p2 + 1]);
          u32 pr;
          asm("v_cvt_pk_bf16_f32 %0, %1, %2" : "=v"(pr) : "v"(va), "v"(vb));
          pk[p2] = pr;
        }
        int row = q * 4 + reg;
        int physc = r ^ row;
        int4 wa; wa.x = (int)pk[0]; wa.y = (int)pk[1]; wa.z = (int)pk[2]; wa.w = (int)pk[3];
        *(int4*)&t1w[(row * 16 + physc) * 8] = wa;
      }
      asm volatile("s_waitcnt lgkmcnt(0)" ::: "memory");
      __builtin_amdgcn_sched_barrier(0);
#pragma unroll
      for (int sm = 0; sm < 4; ++sm) {
        int cc = (4 * sm + q) ^ r;
        short8 af = *(const short8*)&t1w[(r * 16 + cc) * 8];
        int wc = ph * 16 + cc;
#pragma unroll
        for (int nt = 0; nt < 4; ++nt) {
          short8 bf = *(const short8*)&W2L[((nt * 16 + r) * 32 + wc) * 8];
          acc4[nt] = __builtin_amdgcn_mfma_f32_16x16x32_bf16(af, bf, acc4[nt], 0, 0, 0);
        }
      }
    }
    float s0 = 0.f, s1 = 0.f, s2 = 0.f, s3 = 0.f;
#pragma unroll
    for (int nt = 0; nt < 4; ++nt) {
      float bb = B2L[nt * 16 + r];
      s0 += tanh_fast(acc4[nt][0] + bb);
      s1 += tanh_fast(acc4[nt][1] + bb);
      s2 += tanh_fast(acc4[nt][2] + bb);
      s3 += tanh_fast(acc4[nt][3] + bb);
    }
#pragma unroll
    for (int off = 1; off < 16; off <<= 1) {
      s0 += __shfl_xor(s0, off, 64);
      s1 += __shfl_xor(s1, off, 64);
      s2 += __shfl_xor(s2, off, 64);
      s3 += __shfl_xor(s3, off, 64);
    }
    if (r == 0) {
      int base = qt * 16 + q * 4;
      if (use16) {
        es16[base] = f2bfs(s0); es16[base + 1] = f2bfs(s1);
        es16[base + 2] = f2bfs(s2); es16[base + 3] = f2bfs(s3);
      } else {
        float4 o; o.x = s0; o.y = s1; o.z = s2; o.w = s3;
        *(float4*)&es32[base] = o;
      }
    }
  }
}

// ---- k_pre: node embed MLP + gcn_tmp(l=0) + dinv + counter zero --------------
__global__ __launch_bounds__(256) void k_pre(const float* __restrict__ nf,
    const float* __restrict__ w1, const float* __restrict__ b1,
    const float* __restrict__ w2, const float* __restrict__ b2,
    const float* __restrict__ gw, const float* __restrict__ adj,
    float* __restrict__ hid, u16* __restrict__ alls16, float* __restrict__ tmp,
    float* __restrict__ dinv, int* __restrict__ cnt) {
  __shared__ float nfx[4][16];
  __shared__ float t1[4][256];
  __shared__ float nh[4][64];
  int t = threadIdx.x;
  int node0 = blockIdx.x * 4;
  if (blockIdx.x == 0 && t < 16) cnt[t] = 0;
  if (t < 64) nfx[t >> 4][t & 15] = nf[node0 * 16 + t];
  __syncthreads();
  float b1t = b1[t];
  float a0 = b1t, a1 = b1t, a2 = b1t, a3 = b1t;
#pragma unroll
  for (int c = 0; c < 16; ++c) {
    float wv = w1[c * 256 + t];
    a0 += nfx[0][c] * wv; a1 += nfx[1][c] * wv;
    a2 += nfx[2][c] * wv; a3 += nfx[3][c] * wv;
  }
  t1[0][t] = tanh_fast(a0); t1[1][t] = tanh_fast(a1);
  t1[2][t] = tanh_fast(a2); t1[3][t] = tanh_fast(a3);
  __syncthreads();
  int nl = t >> 6, h = t & 63;
  {
    float acc = b2[h];
    for (int c = 0; c < 256; c += 4) {
      float4 xv = *(const float4*)&t1[nl][c];
      acc += xv.x * w2[c * 64 + h] + xv.y * w2[(c + 1) * 64 + h]
           + xv.z * w2[(c + 2) * 64 + h] + xv.w * w2[(c + 3) * 64 + h];
    }
    float v = tanh_fast(acc);
    int node = node0 + nl;
    hid[node * 64 + h] = v;
    alls16[node * 256 + h] = f2bfs(v);
    nh[nl][h] = v;
  }
  __syncthreads();
  {
    float g = 0.f;
    for (int c = 0; c < 64; ++c) g += nh[nl][c] * gw[c * 64 + h];
    tmp[(node0 + nl) * 64 + h] = g;
  }
  {
    int lane = t & 63, row = node0 + (t >> 6);
    float s = 0.f;
#pragma unroll
    for (int u = 0; u < 8; ++u) s += adj[(size_t)row * 512 + u * 64 + lane];
#pragma unroll
    for (int off = 32; off > 0; off >>= 1) s += __shfl_xor(s, off, 64);
    if (lane == 0) dinv[row] = 1.0f / (s + 1.0f);
  }
}

// ------- adjmm0 (R8-proven, 43us class): LDS-staged, 8 rows/block ------------
__global__ __launch_bounds__(256) void k_adjmm0(const float* __restrict__ adj,
    const float* __restrict__ X, const float* __restrict__ dinv,
    float* __restrict__ out, float* __restrict__ vnpart, int* cnt,
    const float* __restrict__ vw1, const float* __restrict__ vb1,
    const float* __restrict__ vg1, const float* __restrict__ vbe1,
    const float* __restrict__ vw2, const float* __restrict__ vb2,
    const float* __restrict__ vg2, const float* __restrict__ vbe2,
    float* __restrict__ vnout, int l) {
  __shared__ float Xt[64 * 64];
  __shared__ float Al[8 * 65];
  __shared__ floatx4 red4[256];
  __shared__ int isLast;
  int t = threadIdx.x;
  int b = blockIdx.x >> 6, it = blockIdx.x & 63;
  int hq = t & 15, slot = t >> 4, row = slot & 7, half = slot >> 3;
  floatx4 acc = (floatx4){0.f, 0.f, 0.f, 0.f};
  for (int jt = 0; jt < 8; ++jt) {
    __syncthreads();
    for (int u = 0; u < 16; ++u) {
      int idx = u * 256 + t;
      int jl = idx >> 6, hh = idx & 63;
      Xt[idx] = X[(b * 512 + jt * 64 + jl) * 64 + hh];
    }
#pragma unroll
    for (int u = 0; u < 2; ++u) {
      int idx = u * 256 + t;
      int il = idx >> 6, jl = idx & 63;
      Al[il * 65 + jl] = adj[((size_t)(b * 512 + it * 8 + il)) * 512 + jt * 64 + jl];
    }
    __syncthreads();
    const float* xp = &Xt[(half * 32) * 64 + hq * 4];
    const float* ap = &Al[row * 65 + half * 32];
#pragma unroll
    for (int jl = 0; jl < 32; ++jl) {
      floatx4 xv = *(const floatx4*)(xp + jl * 64);
      float a = ap[jl];
      acc[0] += a * xv[0]; acc[1] += a * xv[1];
      acc[2] += a * xv[2]; acc[3] += a * xv[3];
    }
  }
  red4[t] = acc;
  __syncthreads();
  if (t < 128) {
    floatx4 s = red4[t], s2 = red4[t + 128];
    int gr = b * 512 + it * 8 + row;
    float d = dinv[gr];
    floatx4 o;
#pragma unroll
    for (int i = 0; i < 4; ++i) o[i] = tanh_fast((s[i] + s2[i]) * d);
    *(floatx4*)&out[gr * 64 + hq * 4] = o;
    red4[t] = o;
  }
  __syncthreads();
  if (t < 16) {
    floatx4 ssum = (floatx4){0.f, 0.f, 0.f, 0.f};
#pragma unroll
    for (int r2 = 0; r2 < 8; ++r2) {
      floatx4 v = red4[r2 * 16 + t];
      ssum[0] += v[0]; ssum[1] += v[1]; ssum[2] += v[2]; ssum[3] += v[3];
    }
    *(floatx4*)&vnpart[(b * 64 + it) * 64 + t * 4] = ssum;
  }
  __threadfence();
  __syncthreads();
  if (t == 0) isLast = (atomicAdd(cnt, 1) == 255);
  __syncthreads();
  if (isLast) {
    __threadfence();
    float* x0 = Xt; float* x1 = Xt + 256; float* y1 = Xt + 768; float* x2 = Xt + 1280;
    {
      int bb = t >> 6, h = t & 63;
      float s = 0.f;
      for (int c = 0; c < 64; ++c) s += vnpart[(bb * 64 + c) * 64 + h];
      x0[t] = s * (1.0f / 512.0f);
    }
    __syncthreads();
    for (int rep = 0; rep < 2; ++rep) {
      int idx = rep * 256 + t;
      int bb = idx >> 7, j = idx & 127;
      float a = vb1[l * 128 + j];
      for (int h = 0; h < 64; ++h) a += x0[bb * 64 + h] * vw1[l * 8192 + h * 128 + j];
      x1[idx] = a;
    }
    __syncthreads();
    if (t < 128) {
      int j = t;
      float a = x1[j], bq = x1[128 + j], c = x1[256 + j], d = x1[384 + j];
      float m = 0.25f * (a + bq + c + d);
      float da = a - m, db = bq - m, dc = c - m, dd = d - m;
      float var = 0.25f * (da * da + db * db + dc * dc + dd * dd);
      float sc = vg1[l * 128 + j] / sqrtf(var + 1e-5f);
      float be = vbe1[l * 128 + j];
      y1[j]       = fmaxf(sc * da + be, 0.f);
      y1[128 + j] = fmaxf(sc * db + be, 0.f);
      y1[256 + j] = fmaxf(sc * dc + be, 0.f);
      y1[384 + j] = fmaxf(sc * dd + be, 0.f);
    }
    __syncthreads();
    {
      int bb = t >> 6, k = t & 63;
      float a = vb2[l * 64 + k];
      for (int j = 0; j < 128; ++j) a += y1[bb * 128 + j] * vw2[l * 8192 + j * 64 + k];
      x2[t] = a;
    }
    __syncthreads();
    if (t < 64) {
      int k = t;
      float a = x2[k], bq = x2[64 + k], c = x2[128 + k], d = x2[192 + k];
      float m = 0.25f * (a + bq + c + d);
      float da = a - m, db = bq - m, dc = c - m, dd = d - m;
      float var = 0.25f * (da * da + db * db + dc * dc + dd * dd);
      float sc = vg2[l * 64 + k] / sqrtf(var + 1e-5f);
      float be = vbe2[l * 64 + k];
      vnout[k]       = fmaxf(sc * da + be, 0.f);
      vnout[64 + k]  = fmaxf(sc * db + be, 0.f);
      vnout[128 + k] = fmaxf(sc * dc + be, 0.f);
      vnout[192 + k] = fmaxf(sc * dd + be, 0.f);
    }
  }
}

// ------- k_gate_comb (R11-proven): adjmm1 staged + comb + gcn_tmp fused ------
__global__ __launch_bounds__(256) void k_gate_comb(
    const float* __restrict__ es32, const u16* __restrict__ es16, int use16,
    const float* __restrict__ hid, const float* __restrict__ vnin,
    const float* __restrict__ cw, const float* __restrict__ cb,
    const float* __restrict__ gw_next,
    u16* __restrict__ alls16, float* __restrict__ tmpout, int l, int do_gcn) {
  __shared__ float Xt[64 * 64];
  __shared__ float Al[8 * 65];
  __shared__ floatx4 red4[256];
  __shared__ float gatedL[8 * 64];
  __shared__ float catL[8 * 128];
  __shared__ float hnL[8 * 64];
  int t = threadIdx.x;
  int b = blockIdx.x >> 6, it = blockIdx.x & 63;
  int hq = t & 15, slot = t >> 4, row = slot & 7, half = slot >> 3;
  floatx4 acc = (floatx4){0.f, 0.f, 0.f, 0.f};
  for (int jt = 0; jt < 8; ++jt) {
    __syncthreads();
    for (int u = 0; u < 16; ++u) {
      int idx = u * 256 + t;
      int jl = idx >> 6, hh = idx & 63;
      Xt[idx] = hid[(b * 512 + jt * 64 + jl) * 64 + hh] + vnin[b * 64 + hh];
    }
#pragma unroll
    for (int u = 0; u < 2; ++u) {
      int idx = u * 256 + t;
      int il = idx >> 6, jl = idx & 63;
      size_t ai = ((size_t)(b * 512 + it * 8 + il)) * 512 + jt * 64 + jl;
      Al[il * 65 + jl] = use16 ? bfu(es16[ai]) : es32[ai];
    }
    __syncthreads();
    const float* xp = &Xt[(half * 32) * 64 + hq * 4];
    const float* ap = &Al[row * 65 + half * 32];
#pragma unroll
    for (int jl = 0; jl < 32; ++jl) {
      floatx4 xv = *(const floatx4*)(xp + jl * 64);
      float a = ap[jl];
      acc[0] += a * xv[0]; acc[1] += a * xv[1];
      acc[2] += a * xv[2]; acc[3] += a * xv[3];
    }
  }
  red4[t] = acc;
  __syncthreads();
  if (t < 128) {
    floatx4 s = red4[t], s2 = red4[t + 128];
    floatx4 o;
#pragma unroll
    for (int i = 0; i < 4; ++i) o[i] = tanh_fast(s[i] + s2[i]);
    *(floatx4*)&gatedL[row * 64 + hq * 4] = o;
  }
  __syncthreads();
#pragma unroll
  for (int u = 0; u < 4; ++u) {
    int idx = u * 256 + t;
    int nl = idx >> 7, c = idx & 127;
    int node = b * 512 + it * 8 + nl;
    catL[idx] = (c < 64) ? (hid[node * 64 + c] + vnin[b * 64 + c])
                         : gatedL[nl * 64 + (c - 64)];
  }
  __syncthreads();
  int nl = t >> 6, h = t & 63;
  float a0 = cb[l * 64 + h], a1 = a0;
  const float* wp = cw + l * 8192 + h;
  for (int c = 0; c < 128; ++c) {
    float wv = wp[c * 64];
    a0 += catL[nl * 128 + c] * wv;
    a1 += catL[(nl + 4) * 128 + c] * wv;
  }
  float v0 = tanh_fast(a0), v1 = tanh_fast(a1);
  int n0 = b * 512 + it * 8 + nl, n1 = n0 + 4;
  alls16[n0 * 256 + (l + 1) * 64 + h] = f2bfs(v0);
  alls16[n1 * 256 + (l + 1) * 64 + h] = f2bfs(v1);
  if (do_gcn) {
    hnL[nl * 64 + h] = v0;
    hnL[(nl + 4) * 64 + h] = v1;
    __syncthreads();
    float g0 = 0.f, g1 = 0.f;
    for (int c = 0; c < 64; ++c) {
      float wv = gw_next[c * 64 + h];
      g0 += hnL[nl * 64 + c] * wv;
      g1 += hnL[(nl + 4) * 64 + c] * wv;
    }
    tmpout[n0 * 64 + h] = g0;
    tmpout[n1 * 64 + h] = g1;
  }
}

// ---- k_lat: latent MLP main body (512 threads, R13-proven) ------------------
__global__ __launch_bounds__(512) void k_lat(const u16* __restrict__ alls16,
    const float* __restrict__ w1, const float* __restrict__ bb1,
    const float* __restrict__ w2, const float* __restrict__ bb2,
    float* __restrict__ latpart) {
  __shared__ float x[8][256];
  __shared__ float t1[8][256];
  __shared__ float red[8][256];
  int t = threadIdx.x;
  int g = t >> 8, tt = t & 255;
  int b = blockIdx.x >> 6, chunk = blockIdx.x & 63;
#pragma unroll
  for (int u = 0; u < 4; ++u)
    x[g * 4 + u][tt] = bfu(alls16[(size_t)(b * 512 + chunk * 8 + g * 4 + u) * 256 + tt]);
  __syncthreads();
  float a1[4];
  float bb = bb1[tt];
#pragma unroll
  for (int u = 0; u < 4; ++u) a1[u] = bb;
  for (int c = 0; c < 256; ++c) {
    float wv = w1[c * 256 + tt];
#pragma unroll
    for (int u = 0; u < 4; ++u) a1[u] += x[g * 4 + u][c] * wv;
  }
#pragma unroll
  for (int u = 0; u < 4; ++u) t1[g * 4 + u][tt] = tanh_fast(a1[u]);
  __syncthreads();
  int quar = tt >> 6, k = tt & 63, c0 = quar * 64;
  float a2[4];
#pragma unroll
  for (int u = 0; u < 4; ++u) a2[u] = 0.f;
  for (int c = 0; c < 64; ++c) {
    float wv = w2[(c0 + c) * 64 + k];
#pragma unroll
    for (int u = 0; u < 4; ++u) a2[u] += t1[g * 4 + u][c0 + c] * wv;
  }
#pragma unroll
  for (int u = 0; u < 4; ++u) red[g * 4 + u][tt] = a2[u];
  __syncthreads();
  if (t < 64) {
    float acc2 = 0.f;
    float b2v = bb2[t];
#pragma unroll
    for (int u = 0; u < 8; ++u) {
      float s = red[u][t] + red[u][t + 64] + red[u][t + 128] + red[u][t + 192] + b2v;
      acc2 += tanh_fast(s);
    }
    latpart[(b * 64 + chunk) * 64 + t] = acc2;
  }
}

// ---- k_final: lat_sum + fc head, grid 4 (one block per batch, R13-proven) ---
__global__ __launch_bounds__(512) void k_final(const float* __restrict__ latpart,
    const float* __restrict__ f1w, const float* __restrict__ f1b,
    const float* __restrict__ f2w, const float* __restrict__ f2b,
    float* __restrict__ outp) {
  __shared__ float lred[512];
  __shared__ float ls[64];
  __shared__ float wred[8];
  int b = blockIdx.x, t = threadIdx.x;
  int z = t & 63, cg = t >> 6;
  float s = 0.f;
  for (int c = cg * 8; c < cg * 8 + 8; ++c) s += latpart[(b * 64 + c) * 64 + z];
  lred[t] = s;
  __syncthreads();
  if (t < 64) {
    float ssum = 0.f;
    for (int gg = 0; gg < 8; ++gg) ssum += lred[gg * 64 + t];
    ls[t] = ssum;
    outp[4 + b * 64 + t] = ssum;   // lat_sum (fp32)
  }
  __syncthreads();
  float acc = f1b[t];
  for (int zz = 0; zz < 64; ++zz) acc += ls[zz] * f1w[zz * 512 + t];
  float h = tanh_fast(acc);
  float p = h * f2w[t];
#pragma unroll
  for (int off = 32; off > 0; off >>= 1) p += __shfl_xor(p, off, 64);
  if ((t & 63) == 0) wred[t >> 6] = p;
  __syncthreads();
  if (t == 0) {
    float a = 0.f;
    for (int wv = 0; wv < 8; ++wv) a += wred[wv];
    outp[b] = a + f2b[0];   // predict (fp32)
  }
}

extern "C" void kernel_launch(void* const* d_in, const int* in_sizes, int n_in,
                              void* d_out, int out_size, void* d_ws, size_t ws_size,
                              hipStream_t stream) {
  const float* adj       = (const float*)d_in[0];
  const float* node_feat = (const float*)d_in[1];
  const float* edge_feat = (const float*)d_in[2];
  const float* nf1_w = (const float*)d_in[3];
  const float* nf1_b = (const float*)d_in[4];
  const float* nf2_w = (const float*)d_in[5];
  const float* nf2_b = (const float*)d_in[6];
  const float* ef1_w = (const float*)d_in[7];
  const float* ef1_b = (const float*)d_in[8];
  const float* ef2_w = (const float*)d_in[9];
  const float* ef2_b = (const float*)d_in[10];
  const float* gcn_w = (const float*)d_in[11];
  const float* vn1_w = (const float*)d_in[12];
  const float* vn1_b = (const float*)d_in[13];
  const float* vn1_g = (const float*)d_in[14];
  const float* vn1_be = (const float*)d_in[15];
  const float* vn2_w = (const float*)d_in[16];
  const float* vn2_b = (const float*)d_in[17];
  const float* vn2_g = (const float*)d_in[18];
  const float* vn2_be = (const float*)d_in[19];
  const float* comb_w = (const float*)d_in[20];
  const float* comb_b = (const float*)d_in[21];
  const float* lat1_w = (const float*)d_in[22];
  const float* lat1_b = (const float*)d_in[23];
  const float* lat2_w = (const float*)d_in[24];
  const float* lat2_b = (const float*)d_in[25];
  const float* fc1_w = (const float*)d_in[26];
  const float* fc1_b = (const float*)d_in[27];
  const float* fc2_w = (const float*)d_in[28];
  const float* fc2_b = (const float*)d_in[29];

  const int use16 = (ws_size < (size_t)12 * 1024 * 1024) ? 1 : 0;
  char* p = (char*)d_ws;
  float* es32 = (float*)p;
  u16*   es16 = (u16*)p;
  size_t es_bytes = use16 ? (size_t)1048576 * 2 : (size_t)1048576 * 4;
  u16*   alls16  = (u16*)(p + es_bytes);      // 524288 u16
  float* hid     = (float*)(alls16 + 524288); // 131072 f32
  float* tmp     = hid + 131072;              // 131072 (gcn tmp)
  float* dinv    = tmp + 131072;              // 2048
  float* vnpart  = dinv + 2048;               // 16384
  float* vn      = vnpart + 16384;            // 256
  float* latpart = vn + 256;                  // 16384
  int*   cnt     = (int*)(latpart + 16384);   // 16

  k_pre<<<512, 256, 0, stream>>>(node_feat, nf1_w, nf1_b, nf2_w, nf2_b,
                                 gcn_w, adj, hid, alls16, tmp, dinv, cnt);
  k_edge<<<256, 1024, 0, stream>>>(edge_feat, ef1_w, ef1_b, ef2_w, ef2_b,
                                   es32, es16, use16);
  for (int l = 0; l < 3; ++l) {
    k_adjmm0<<<256, 256, 0, stream>>>(adj, tmp, dinv, hid, vnpart, cnt + l,
        vn1_w, vn1_b, vn1_g, vn1_be, vn2_w, vn2_b, vn2_g, vn2_be, vn, l);
    k_gate_comb<<<256, 256, 0, stream>>>(es32, es16, use16, hid, vn,
        comb_w, comb_b, gcn_w + (l + 1) * 4096, alls16, tmp, l, (l < 2) ? 1 : 0);
  }
  k_lat<<<256, 512, 0, stream>>>(alls16, lat1_w, lat1_b, lat2_w, lat2_b, latpart);
  k_final<<<4, 512, 0, stream>>>(latpart, fc1_w, fc1_b, fc2_w, fc2_b,
                                 (float*)d_out);
}

// Round 16
// 425.820 us; speedup vs baseline: 1.3360x; 1.0229x over previous
//
#include <hip/hip_runtime.h>
#include <math.h>

typedef unsigned short u16;
typedef unsigned int u32;

typedef __attribute__((ext_vector_type(8))) short short8;
typedef __attribute__((ext_vector_type(4))) float floatx4;

#define NTILES 16384  // B*N*N/64

__device__ __forceinline__ float bfu(u16 u) { return __uint_as_float(((u32)u) << 16); }
__device__ __forceinline__ u16 f2bfs(float f) {
  u32 x = __float_as_uint(f);
  return (u16)((x + 0x7FFFu + ((x >> 16) & 1u)) >> 16);
}
__device__ __forceinline__ float tanh_fast(float x) {
  float e = __builtin_amdgcn_exp2f(x * 2.885390081777927f);
  return 1.0f - 2.0f * __builtin_amdgcn_rcpf(e + 1.0f);
}

// ------ edge MLP -> e_sum (R8-proven: ~131us, transcendental-pipe floor) -----
__global__ __attribute__((amdgpu_flat_work_group_size(1024, 1024)))
__attribute__((amdgpu_waves_per_eu(4, 4)))
void k_edge(const float* __restrict__ ef,
    const float* __restrict__ w1, const float* __restrict__ b1,
    const float* __restrict__ w2, const float* __restrict__ b2,
    float* __restrict__ es32, u16* __restrict__ es16, int use16) {
  __shared__ __align__(16) short T1[16 * 2048];   // per-wave 4KB
  __shared__ __align__(16) short W2L[16384];      // swizzled
  __shared__ __align__(16) short W1L[2 * 2056];
  __shared__ __align__(16) float B1L[256];
  __shared__ __align__(16) float B2L[64];
  int t = threadIdx.x;
  int lane = t & 63, w = t >> 6, q = lane >> 4, r = lane & 15;

  for (int u = 0; u < 16; ++u) {
    int flat = u * 1024 + t;
    int k = flat >> 6, n = flat & 63;
    int c = k >> 3, j = k & 7;
    int physc = (c & 16) | ((c & 15) ^ (n & 15));
    W2L[(n * 32 + physc) * 8 + j] = (short)f2bfs(w2[flat]);
  }
  if (t < 512) {
    int hilo = t >> 8, idx = t & 255;
    int gu = idx >> 4, rr = idx & 15;
    int feat = (gu < 8) ? (rr * 8 + gu) : (120 + rr * 8 + gu);
    short8 v;
#pragma unroll
    for (int j = 0; j < 8; ++j) {
      float x = w1[j * 256 + feat];
      u32 xb = __float_as_uint(x);
      u16 hi = (u16)(xb >> 16);
      v[j] = hilo ? (short)f2bfs(x - bfu(hi)) : (short)hi;
    }
    *(short8*)&W1L[hilo * 2056 + idx * 8] = v;
  }
  if (t < 256) B1L[t] = b1[t];
  if (t < 64)  B2L[t] = b2[t];
  __syncthreads();

  short* t1w = &T1[w * 2048];
  const int hb = (q >> 1) * 2056;
  const int nw = gridDim.x * 16;
  int qt = blockIdx.x * 16 + w;
  float4 e0, e1;
  {
    const float4* ep = (const float4*)(ef + (size_t)qt * 128 + (size_t)r * 8);
    e0 = ep[0]; e1 = ep[1];
  }

  for (; qt < 4 * NTILES; qt += nw) {
    float ev[8] = {e0.x, e0.y, e0.z, e0.w, e1.x, e1.y, e1.z, e1.w};
    short8 af1;
#pragma unroll
    for (int j = 0; j < 8; ++j) {
      u32 xb = __float_as_uint(ev[j]);
      u16 hi = (u16)(xb >> 16);
      af1[j] = (q & 1) ? (short)f2bfs(ev[j] - bfu(hi)) : (short)hi;
    }
    int nqt = qt + nw;
    if (nqt < 4 * NTILES) {
      const float4* ep = (const float4*)(ef + (size_t)nqt * 128 + (size_t)r * 8);
      e0 = ep[0]; e1 = ep[1];
    }
    floatx4 acc4[4];
#pragma unroll
    for (int nt = 0; nt < 4; ++nt) acc4[nt] = (floatx4){0.f, 0.f, 0.f, 0.f};
#pragma unroll
    for (int ph = 0; ph < 2; ++ph) {
      floatx4 c1[8];
#pragma unroll
      for (int u = 0; u < 8; ++u) c1[u] = (floatx4){0.f, 0.f, 0.f, 0.f};
#pragma unroll
      for (int u = 0; u < 8; ++u) {
        short8 bf = *(const short8*)&W1L[hb + ((ph * 8 + u) * 16 + r) * 8];
        c1[u] = __builtin_amdgcn_mfma_f32_16x16x32_bf16(af1, bf, c1[u], 0, 0, 0);
      }
      asm volatile("s_waitcnt lgkmcnt(0)" ::: "memory");
      __builtin_amdgcn_sched_barrier(0);
      const float4* bp = (const float4*)&B1L[ph * 128 + r * 8];
      float4 bA = bp[0], bB = bp[1];
      float bias[8] = {bA.x, bA.y, bA.z, bA.w, bB.x, bB.y, bB.z, bB.w};
#pragma unroll
      for (int reg = 0; reg < 4; ++reg) {
        u32 pk[4];
#pragma unroll
        for (int p2 = 0; p2 < 4; ++p2) {
          float va = tanh_fast(c1[2 * p2][reg] + bias[2 * p2]);
          float vb = tanh_fast(c1[2 * p2 + 1][reg] + bias[2 * p2 + 1]);
          u32 pr;
          asm("v_cvt_pk_bf16_f32 %0, %1, %2" : "=v"(pr) : "v"(va), "v"(vb));
          pk[p2] = pr;
        }
        int row = q * 4 + reg;
        int physc = r ^ row;
        int4 wa; wa.x = (int)pk[0]; wa.y = (int)pk[1]; wa.z = (int)pk[2]; wa.w = (int)pk[3];
        *(int4*)&t1w[(row * 16 + physc) * 8] = wa;
      }
      asm volatile("s_waitcnt lgkmcnt(0)" ::: "memory");
      __builtin_amdgcn_sched_barrier(0);
#pragma unroll
      for (int sm = 0; sm < 4; ++sm) {
        int cc = (4 * sm + q) ^ r;
        short8 af = *(const short8*)&t1w[(r * 16 + cc) * 8];
        int wc = ph * 16 + cc;
#pragma unroll
        for (int nt = 0; nt < 4; ++nt) {
          short8 bf = *(const short8*)&W2L[((nt * 16 + r) * 32 + wc) * 8];
          acc4[nt] = __builtin_amdgcn_mfma_f32_16x16x32_bf16(af, bf, acc4[nt], 0, 0, 0);
        }
      }
    }
    float s0 = 0.f, s1 = 0.f, s2 = 0.f, s3 = 0.f;
#pragma unroll
    for (int nt = 0; nt < 4; ++nt) {
      float bb = B2L[nt * 16 + r];
      s0 += tanh_fast(acc4[nt][0] + bb);
      s1 += tanh_fast(acc4[nt][1] + bb);
      s2 += tanh_fast(acc4[nt][2] + bb);
      s3 += tanh_fast(acc4[nt][3] + bb);
    }
#pragma unroll
    for (int off = 1; off < 16; off <<= 1) {
      s0 += __shfl_xor(s0, off, 64);
      s1 += __shfl_xor(s1, off, 64);
      s2 += __shfl_xor(s2, off, 64);
      s3 += __shfl_xor(s3, off, 64);
    }
    if (r == 0) {
      int base = qt * 16 + q * 4;
      if (use16) {
        es16[base] = f2bfs(s0); es16[base + 1] = f2bfs(s1);
        es16[base + 2] = f2bfs(s2); es16[base + 3] = f2bfs(s3);
      } else {
        float4 o; o.x = s0; o.y = s1; o.z = s2; o.w = s3;
        *(float4*)&es32[base] = o;
      }
    }
  }
}

// ---- k_pre: node embed MLP + gcn_tmp(l=0) + dinv + counter zero --------------
__global__ __launch_bounds__(256) void k_pre(const float* __restrict__ nf,
    const float* __restrict__ w1, const float* __restrict__ b1,
    const float* __restrict__ w2, const float* __restrict__ b2,
    const float* __restrict__ gw, const float* __restrict__ adj,
    float* __restrict__ hid, u16* __restrict__ alls16, float* __restrict__ tmp,
    float* __restrict__ dinv, int* __restrict__ cnt) {
  __shared__ float nfx[4][16];
  __shared__ float t1[4][256];
  __shared__ float nh[4][64];
  int t = threadIdx.x;
  int node0 = blockIdx.x * 4;
  if (blockIdx.x == 0 && t < 16) cnt[t] = 0;
  if (t < 64) nfx[t >> 4][t & 15] = nf[node0 * 16 + t];
  __syncthreads();
  float b1t = b1[t];
  float a0 = b1t, a1 = b1t, a2 = b1t, a3 = b1t;
#pragma unroll
  for (int c = 0; c < 16; ++c) {
    float wv = w1[c * 256 + t];
    a0 += nfx[0][c] * wv; a1 += nfx[1][c] * wv;
    a2 += nfx[2][c] * wv; a3 += nfx[3][c] * wv;
  }
  t1[0][t] = tanh_fast(a0); t1[1][t] = tanh_fast(a1);
  t1[2][t] = tanh_fast(a2); t1[3][t] = tanh_fast(a3);
  __syncthreads();
  int nl = t >> 6, h = t & 63;
  {
    float acc = b2[h];
    for (int c = 0; c < 256; c += 4) {
      float4 xv = *(const float4*)&t1[nl][c];
      acc += xv.x * w2[c * 64 + h] + xv.y * w2[(c + 1) * 64 + h]
           + xv.z * w2[(c + 2) * 64 + h] + xv.w * w2[(c + 3) * 64 + h];
    }
    float v = tanh_fast(acc);
    int node = node0 + nl;
    hid[node * 64 + h] = v;
    alls16[node * 256 + h] = f2bfs(v);
    nh[nl][h] = v;
  }
  __syncthreads();
  {
    float g = 0.f;
    for (int c = 0; c < 64; ++c) g += nh[nl][c] * gw[c * 64 + h];
    tmp[(node0 + nl) * 64 + h] = g;
  }
  {
    int lane = t & 63, row = node0 + (t >> 6);
    float s = 0.f;
#pragma unroll
    for (int u = 0; u < 8; ++u) s += adj[(size_t)row * 512 + u * 64 + lane];
#pragma unroll
    for (int off = 32; off > 0; off >>= 1) s += __shfl_xor(s, off, 64);
    if (lane == 0) dinv[row] = 1.0f / (s + 1.0f);
  }
}

// ------- adjmm0 R16: R8 structure + register double-buffer (T14 async-stage).
// Loads for jt+1 issue BEFORE the compute phase; latency hides under LDS/FMA.
// Numerics bit-identical to R8 form.
__global__ __launch_bounds__(256) void k_adjmm0(const float* __restrict__ adj,
    const float* __restrict__ X, const float* __restrict__ dinv,
    float* __restrict__ out, float* __restrict__ vnpart, int* cnt,
    const float* __restrict__ vw1, const float* __restrict__ vb1,
    const float* __restrict__ vg1, const float* __restrict__ vbe1,
    const float* __restrict__ vw2, const float* __restrict__ vb2,
    const float* __restrict__ vg2, const float* __restrict__ vbe2,
    float* __restrict__ vnout, int l) {
  __shared__ float Xt[64 * 64];
  __shared__ float Al[8 * 65];
  __shared__ floatx4 red4[256];
  __shared__ int isLast;
  int t = threadIdx.x;
  int b = blockIdx.x >> 6, it = blockIdx.x & 63;
  int hq = t & 15, slot = t >> 4, row = slot & 7, half = slot >> 3;
  floatx4 acc = (floatx4){0.f, 0.f, 0.f, 0.f};
  float xreg[16], areg[2];
  // prefetch jt = 0
#pragma unroll
  for (int u = 0; u < 16; ++u) {
    int idx = u * 256 + t;
    int jl = idx >> 6, hh = idx & 63;
    xreg[u] = X[(b * 512 + jl) * 64 + hh];
  }
#pragma unroll
  for (int u = 0; u < 2; ++u) {
    int idx = u * 256 + t;
    int il = idx >> 6, jl = idx & 63;
    areg[u] = adj[((size_t)(b * 512 + it * 8 + il)) * 512 + jl];
  }
  for (int jt = 0; jt < 8; ++jt) {
    __syncthreads();
#pragma unroll
    for (int u = 0; u < 16; ++u) Xt[u * 256 + t] = xreg[u];
#pragma unroll
    for (int u = 0; u < 2; ++u) {
      int idx = u * 256 + t;
      int il = idx >> 6, jl = idx & 63;
      Al[il * 65 + jl] = areg[u];
    }
    __syncthreads();
    if (jt < 7) {   // issue next tile's loads BEFORE compute (latency hidden)
#pragma unroll
      for (int u = 0; u < 16; ++u) {
        int idx = u * 256 + t;
        int jl = idx >> 6, hh = idx & 63;
        xreg[u] = X[(b * 512 + (jt + 1) * 64 + jl) * 64 + hh];
      }
#pragma unroll
      for (int u = 0; u < 2; ++u) {
        int idx = u * 256 + t;
        int il = idx >> 6, jl = idx & 63;
        areg[u] = adj[((size_t)(b * 512 + it * 8 + il)) * 512 + (jt + 1) * 64 + jl];
      }
    }
    const float* xp = &Xt[(half * 32) * 64 + hq * 4];
    const float* ap = &Al[row * 65 + half * 32];
#pragma unroll
    for (int jl = 0; jl < 32; ++jl) {
      floatx4 xv = *(const floatx4*)(xp + jl * 64);
      float a = ap[jl];
      acc[0] += a * xv[0]; acc[1] += a * xv[1];
      acc[2] += a * xv[2]; acc[3] += a * xv[3];
    }
  }
  red4[t] = acc;
  __syncthreads();
  if (t < 128) {
    floatx4 s = red4[t], s2 = red4[t + 128];
    int gr = b * 512 + it * 8 + row;
    float d = dinv[gr];
    floatx4 o;
#pragma unroll
    for (int i = 0; i < 4; ++i) o[i] = tanh_fast((s[i] + s2[i]) * d);
    *(floatx4*)&out[gr * 64 + hq * 4] = o;
    red4[t] = o;
  }
  __syncthreads();
  if (t < 16) {
    floatx4 ssum = (floatx4){0.f, 0.f, 0.f, 0.f};
#pragma unroll
    for (int r2 = 0; r2 < 8; ++r2) {
      floatx4 v = red4[r2 * 16 + t];
      ssum[0] += v[0]; ssum[1] += v[1]; ssum[2] += v[2]; ssum[3] += v[3];
    }
    *(floatx4*)&vnpart[(b * 64 + it) * 64 + t * 4] = ssum;
  }
  __threadfence();
  __syncthreads();
  if (t == 0) isLast = (atomicAdd(cnt, 1) == 255);
  __syncthreads();
  if (isLast) {
    __threadfence();
    float* x0 = Xt; float* x1 = Xt + 256; float* y1 = Xt + 768; float* x2 = Xt + 1280;
    {
      int bb = t >> 6, h = t & 63;
      float s = 0.f;
      for (int c = 0; c < 64; ++c) s += vnpart[(bb * 64 + c) * 64 + h];
      x0[t] = s * (1.0f / 512.0f);
    }
    __syncthreads();
    for (int rep = 0; rep < 2; ++rep) {
      int idx = rep * 256 + t;
      int bb = idx >> 7, j = idx & 127;
      float a = vb1[l * 128 + j];
      for (int h = 0; h < 64; ++h) a += x0[bb * 64 + h] * vw1[l * 8192 + h * 128 + j];
      x1[idx] = a;
    }
    __syncthreads();
    if (t < 128) {
      int j = t;
      float a = x1[j], bq = x1[128 + j], c = x1[256 + j], d = x1[384 + j];
      float m = 0.25f * (a + bq + c + d);
      float da = a - m, db = bq - m, dc = c - m, dd = d - m;
      float var = 0.25f * (da * da + db * db + dc * dc + dd * dd);
      float sc = vg1[l * 128 + j] / sqrtf(var + 1e-5f);
      float be = vbe1[l * 128 + j];
      y1[j]       = fmaxf(sc * da + be, 0.f);
      y1[128 + j] = fmaxf(sc * db + be, 0.f);
      y1[256 + j] = fmaxf(sc * dc + be, 0.f);
      y1[384 + j] = fmaxf(sc * dd + be, 0.f);
    }
    __syncthreads();
    {
      int bb = t >> 6, k = t & 63;
      float a = vb2[l * 64 + k];
      for (int j = 0; j < 128; ++j) a += y1[bb * 128 + j] * vw2[l * 8192 + j * 64 + k];
      x2[t] = a;
    }
    __syncthreads();
    if (t < 64) {
      int k = t;
      float a = x2[k], bq = x2[64 + k], c = x2[128 + k], d = x2[192 + k];
      float m = 0.25f * (a + bq + c + d);
      float da = a - m, db = bq - m, dc = c - m, dd = d - m;
      float var = 0.25f * (da * da + db * db + dc * dc + dd * dd);
      float sc = vg2[l * 64 + k] / sqrtf(var + 1e-5f);
      float be = vbe2[l * 64 + k];
      vnout[k]       = fmaxf(sc * da + be, 0.f);
      vnout[64 + k]  = fmaxf(sc * db + be, 0.f);
      vnout[128 + k] = fmaxf(sc * dc + be, 0.f);
      vnout[192 + k] = fmaxf(sc * dd + be, 0.f);
    }
  }
}

// ------- k_gate_comb R16: R11 structure + register double-buffer -------------
__global__ __launch_bounds__(256) void k_gate_comb(
    const float* __restrict__ es32, const u16* __restrict__ es16, int use16,
    const float* __restrict__ hid, const float* __restrict__ vnin,
    const float* __restrict__ cw, const float* __restrict__ cb,
    const float* __restrict__ gw_next,
    u16* __restrict__ alls16, float* __restrict__ tmpout, int l, int do_gcn) {
  __shared__ float Xt[64 * 64];
  __shared__ float Al[8 * 65];
  __shared__ floatx4 red4[256];
  __shared__ float gatedL[8 * 64];
  __shared__ float catL[8 * 128];
  __shared__ float hnL[8 * 64];
  int t = threadIdx.x;
  int b = blockIdx.x >> 6, it = blockIdx.x & 63;
  int hq = t & 15, slot = t >> 4, row = slot & 7, half = slot >> 3;
  float vnl = vnin[b * 64 + (t & 63)];   // hh = (u*256+t)&63 = t&63 for all u
  floatx4 acc = (floatx4){0.f, 0.f, 0.f, 0.f};
  float xreg[16], areg[2];
#pragma unroll
  for (int u = 0; u < 16; ++u) {
    int idx = u * 256 + t;
    int jl = idx >> 6, hh = idx & 63;
    xreg[u] = hid[(b * 512 + jl) * 64 + hh];
  }
#pragma unroll
  for (int u = 0; u < 2; ++u) {
    int idx = u * 256 + t;
    int il = idx >> 6, jl = idx & 63;
    size_t ai = ((size_t)(b * 512 + it * 8 + il)) * 512 + jl;
    areg[u] = use16 ? bfu(es16[ai]) : es32[ai];
  }
  for (int jt = 0; jt < 8; ++jt) {
    __syncthreads();
#pragma unroll
    for (int u = 0; u < 16; ++u) Xt[u * 256 + t] = xreg[u] + vnl;
#pragma unroll
    for (int u = 0; u < 2; ++u) {
      int idx = u * 256 + t;
      int il = idx >> 6, jl = idx & 63;
      Al[il * 65 + jl] = areg[u];
    }
    __syncthreads();
    if (jt < 7) {
#pragma unroll
      for (int u = 0; u < 16; ++u) {
        int idx = u * 256 + t;
        int jl = idx >> 6, hh = idx & 63;
        xreg[u] = hid[(b * 512 + (jt + 1) * 64 + jl) * 64 + hh];
      }
#pragma unroll
      for (int u = 0; u < 2; ++u) {
        int idx = u * 256 + t;
        int il = idx >> 6, jl = idx & 63;
        size_t ai = ((size_t)(b * 512 + it * 8 + il)) * 512 + (jt + 1) * 64 + jl;
        areg[u] = use16 ? bfu(es16[ai]) : es32[ai];
      }
    }
    const float* xp = &Xt[(half * 32) * 64 + hq * 4];
    const float* ap = &Al[row * 65 + half * 32];
#pragma unroll
    for (int jl = 0; jl < 32; ++jl) {
      floatx4 xv = *(const floatx4*)(xp + jl * 64);
      float a = ap[jl];
      acc[0] += a * xv[0]; acc[1] += a * xv[1];
      acc[2] += a * xv[2]; acc[3] += a * xv[3];
    }
  }
  red4[t] = acc;
  __syncthreads();
  if (t < 128) {
    floatx4 s = red4[t], s2 = red4[t + 128];
    floatx4 o;
#pragma unroll
    for (int i = 0; i < 4; ++i) o[i] = tanh_fast(s[i] + s2[i]);
    *(floatx4*)&gatedL[row * 64 + hq * 4] = o;
  }
  __syncthreads();
#pragma unroll
  for (int u = 0; u < 4; ++u) {
    int idx = u * 256 + t;
    int nl = idx >> 7, c = idx & 127;
    int node = b * 512 + it * 8 + nl;
    catL[idx] = (c < 64) ? (hid[node * 64 + c] + vnin[b * 64 + c])
                         : gatedL[nl * 64 + (c - 64)];
  }
  __syncthreads();
  int nl = t >> 6, h = t & 63;
  float a0 = cb[l * 64 + h], a1 = a0;
  const float* wp = cw + l * 8192 + h;
  for (int c = 0; c < 128; ++c) {
    float wv = wp[c * 64];
    a0 += catL[nl * 128 + c] * wv;
    a1 += catL[(nl + 4) * 128 + c] * wv;
  }
  float v0 = tanh_fast(a0), v1 = tanh_fast(a1);
  int n0 = b * 512 + it * 8 + nl, n1 = n0 + 4;
  alls16[n0 * 256 + (l + 1) * 64 + h] = f2bfs(v0);
  alls16[n1 * 256 + (l + 1) * 64 + h] = f2bfs(v1);
  if (do_gcn) {
    hnL[nl * 64 + h] = v0;
    hnL[(nl + 4) * 64 + h] = v1;
    __syncthreads();
    float g0 = 0.f, g1 = 0.f;
    for (int c = 0; c < 64; ++c) {
      float wv = gw_next[c * 64 + h];
      g0 += hnL[nl * 64 + c] * wv;
      g1 += hnL[(nl + 4) * 64 + c] * wv;
    }
    tmpout[n0 * 64 + h] = g0;
    tmpout[n1 * 64 + h] = g1;
  }
}

// ---- k_lat: latent MLP main body (512 threads, R13-proven) ------------------
__global__ __launch_bounds__(512) void k_lat(const u16* __restrict__ alls16,
    const float* __restrict__ w1, const float* __restrict__ bb1,
    const float* __restrict__ w2, const float* __restrict__ bb2,
    float* __restrict__ latpart) {
  __shared__ float x[8][256];
  __shared__ float t1[8][256];
  __shared__ float red[8][256];
  int t = threadIdx.x;
  int g = t >> 8, tt = t & 255;
  int b = blockIdx.x >> 6, chunk = blockIdx.x & 63;
#pragma unroll
  for (int u = 0; u < 4; ++u)
    x[g * 4 + u][tt] = bfu(alls16[(size_t)(b * 512 + chunk * 8 + g * 4 + u) * 256 + tt]);
  __syncthreads();
  float a1[4];
  float bb = bb1[tt];
#pragma unroll
  for (int u = 0; u < 4; ++u) a1[u] = bb;
  for (int c = 0; c < 256; ++c) {
    float wv = w1[c * 256 + tt];
#pragma unroll
    for (int u = 0; u < 4; ++u) a1[u] += x[g * 4 + u][c] * wv;
  }
#pragma unroll
  for (int u = 0; u < 4; ++u) t1[g * 4 + u][tt] = tanh_fast(a1[u]);
  __syncthreads();
  int quar = tt >> 6, k = tt & 63, c0 = quar * 64;
  float a2[4];
#pragma unroll
  for (int u = 0; u < 4; ++u) a2[u] = 0.f;
  for (int c = 0; c < 64; ++c) {
    float wv = w2[(c0 + c) * 64 + k];
#pragma unroll
    for (int u = 0; u < 4; ++u) a2[u] += t1[g * 4 + u][c0 + c] * wv;
  }
#pragma unroll
  for (int u = 0; u < 4; ++u) red[g * 4 + u][tt] = a2[u];
  __syncthreads();
  if (t < 64) {
    float acc2 = 0.f;
    float b2v = bb2[t];
#pragma unroll
    for (int u = 0; u < 8; ++u) {
      float s = red[u][t] + red[u][t + 64] + red[u][t + 128] + red[u][t + 192] + b2v;
      acc2 += tanh_fast(s);
    }
    latpart[(b * 64 + chunk) * 64 + t] = acc2;
  }
}

// ---- k_final: lat_sum + fc head, grid 4 (one block per batch, R13-proven) ---
__global__ __launch_bounds__(512) void k_final(const float* __restrict__ latpart,
    const float* __restrict__ f1w, const float* __restrict__ f1b,
    const float* __restrict__ f2w, const float* __restrict__ f2b,
    float* __restrict__ outp) {
  __shared__ float lred[512];
  __shared__ float ls[64];
  __shared__ float wred[8];
  int b = blockIdx.x, t = threadIdx.x;
  int z = t & 63, cg = t >> 6;
  float s = 0.f;
  for (int c = cg * 8; c < cg * 8 + 8; ++c) s += latpart[(b * 64 + c) * 64 + z];
  lred[t] = s;
  __syncthreads();
  if (t < 64) {
    float ssum = 0.f;
    for (int gg = 0; gg < 8; ++gg) ssum += lred[gg * 64 + t];
    ls[t] = ssum;
    outp[4 + b * 64 + t] = ssum;   // lat_sum (fp32)
  }
  __syncthreads();
  float acc = f1b[t];
  for (int zz = 0; zz < 64; ++zz) acc += ls[zz] * f1w[zz * 512 + t];
  float h = tanh_fast(acc);
  float p = h * f2w[t];
#pragma unroll
  for (int off = 32; off > 0; off >>= 1) p += __shfl_xor(p, off, 64);
  if ((t & 63) == 0) wred[t >> 6] = p;
  __syncthreads();
  if (t == 0) {
    float a = 0.f;
    for (int wv = 0; wv < 8; ++wv) a += wred[wv];
    outp[b] = a + f2b[0];   // predict (fp32)
  }
}

extern "C" void kernel_launch(void* const* d_in, const int* in_sizes, int n_in,
                              void* d_out, int out_size, void* d_ws, size_t ws_size,
                              hipStream_t stream) {
  const float* adj       = (const float*)d_in[0];
  const float* node_feat = (const float*)d_in[1];
  const float* edge_feat = (const float*)d_in[2];
  const float* nf1_w = (const float*)d_in[3];
  const float* nf1_b = (const float*)d_in[4];
  const float* nf2_w = (const float*)d_in[5];
  const float* nf2_b = (const float*)d_in[6];
  const float* ef1_w = (const float*)d_in[7];
  const float* ef1_b = (const float*)d_in[8];
  const float* ef2_w = (const float*)d_in[9];
  const float* ef2_b = (const float*)d_in[10];
  const float* gcn_w = (const float*)d_in[11];
  const float* vn1_w = (const float*)d_in[12];
  const float* vn1_b = (const float*)d_in[13];
  const float* vn1_g = (const float*)d_in[14];
  const float* vn1_be = (const float*)d_in[15];
  const float* vn2_w = (const float*)d_in[16];
  const float* vn2_b = (const float*)d_in[17];
  const float* vn2_g = (const float*)d_in[18];
  const float* vn2_be = (const float*)d_in[19];
  const float* comb_w = (const float*)d_in[20];
  const float* comb_b = (const float*)d_in[21];
  const float* lat1_w = (const float*)d_in[22];
  const float* lat1_b = (const float*)d_in[23];
  const float* lat2_w = (const float*)d_in[24];
  const float* lat2_b = (const float*)d_in[25];
  const float* fc1_w = (const float*)d_in[26];
  const float* fc1_b = (const float*)d_in[27];
  const float* fc2_w = (const float*)d_in[28];
  const float* fc2_b = (const float*)d_in[29];

  const int use16 = (ws_size < (size_t)12 * 1024 * 1024) ? 1 : 0;
  char* p = (char*)d_ws;
  float* es32 = (float*)p;
  u16*   es16 = (u16*)p;
  size_t es_bytes = use16 ? (size_t)1048576 * 2 : (size_t)1048576 * 4;
  u16*   alls16  = (u16*)(p + es_bytes);      // 524288 u16
  float* hid     = (float*)(alls16 + 524288); // 131072 f32
  float* tmp     = hid + 131072;              // 131072 (gcn tmp)
  float* dinv    = tmp + 131072;              // 2048
  float* vnpart  = dinv + 2048;               // 16384
  float* vn      = vnpart + 16384;            // 256
  float* latpart = vn + 256;                  // 16384
  int*   cnt     = (int*)(latpart + 16384);   // 16

  k_pre<<<512, 256, 0, stream>>>(node_feat, nf1_w, nf1_b, nf2_w, nf2_b,
                                 gcn_w, adj, hid, alls16, tmp, dinv, cnt);
  k_edge<<<256, 1024, 0, stream>>>(edge_feat, ef1_w, ef1_b, ef2_w, ef2_b,
                                   es32, es16, use16);
  for (int l = 0; l < 3; ++l) {
    k_adjmm0<<<256, 256, 0, stream>>>(adj, tmp, dinv, hid, vnpart, cnt + l,
        vn1_w, vn1_b, vn1_g, vn1_be, vn2_w, vn2_b, vn2_g, vn2_be, vn, l);
    k_gate_comb<<<256, 256, 0, stream>>>(es32, es16, use16, hid, vn,
        comb_w, comb_b, gcn_w + (l + 1) * 4096, alls16, tmp, l, (l < 2) ? 1 : 0);
  }
  k_lat<<<256, 512, 0, stream>>>(alls16, lat1_w, lat1_b, lat2_w, lat2_b, latpart);
  k_final<<<4, 512, 0, stream>>>(latpart, fc1_w, fc1_b, fc2_w, fc2_b,
                                 (float*)d_out);
}